// Round 6
// baseline (24698.624 us; speedup 1.0000x reference)
//
#include <hip/hip_runtime.h>

// Problem constants (from reference): B=32, T=2048, D_IN=D_OUT=512, fp32.
constexpr int B = 32, T = 2048, D = 512;

// ---------------- Kernel 1: xw = x @ W + b, written in-place into d_out ----
__global__ __launch_bounds__(256) void xw_gemm(
    const float* __restrict__ A, const float* __restrict__ W,
    const float* __restrict__ bias, float* __restrict__ C) {
  __shared__ float As[16][68];
  __shared__ float Bs[16][68];
  const int tid = threadIdx.x;
  const int M0 = blockIdx.y * 64, N0 = blockIdx.x * 64;
  const int tn = tid & 15, tm = tid >> 4;
  const int rA = tid >> 2, kA = (tid & 3) << 2;
  const int kB = tid >> 4, nB = (tid & 15) << 2;
  float acc[4][4] = {};
  for (int k0 = 0; k0 < 512; k0 += 16) {
    float4 a4 = *(const float4*)&A[(size_t)(M0 + rA) * 512 + k0 + kA];
    As[kA + 0][rA] = a4.x;
    As[kA + 1][rA] = a4.y;
    As[kA + 2][rA] = a4.z;
    As[kA + 3][rA] = a4.w;
    *(float4*)&Bs[kB][nB] = *(const float4*)&W[(size_t)(k0 + kB) * 512 + N0 + nB];
    __syncthreads();
#pragma unroll
    for (int k = 0; k < 16; ++k) {
      float a0 = As[k][tm * 4 + 0], a1 = As[k][tm * 4 + 1];
      float a2 = As[k][tm * 4 + 2], a3 = As[k][tm * 4 + 3];
      float b0 = Bs[k][tn * 4 + 0], b1 = Bs[k][tn * 4 + 1];
      float b2 = Bs[k][tn * 4 + 2], b3 = Bs[k][tn * 4 + 3];
      acc[0][0] += a0 * b0; acc[0][1] += a0 * b1; acc[0][2] += a0 * b2; acc[0][3] += a0 * b3;
      acc[1][0] += a1 * b0; acc[1][1] += a1 * b1; acc[1][2] += a1 * b2; acc[1][3] += a1 * b3;
      acc[2][0] += a2 * b0; acc[2][1] += a2 * b1; acc[2][2] += a2 * b2; acc[2][3] += a2 * b3;
      acc[3][0] += a3 * b0; acc[3][1] += a3 * b1; acc[3][2] += a3 * b2; acc[3][3] += a3 * b3;
    }
    __syncthreads();
  }
#pragma unroll
  for (int i = 0; i < 4; ++i) {
    const size_t row = (size_t)(M0 + tm * 4 + i);
    float4 v;
    v.x = acc[i][0] + bias[N0 + tn * 4 + 0];
    v.y = acc[i][1] + bias[N0 + tn * 4 + 1];
    v.z = acc[i][2] + bias[N0 + tn * 4 + 2];
    v.w = acc[i][3] + bias[N0 + tn * 4 + 3];
    *(float4*)&C[row * 512 + N0 + tn * 4] = v;
  }
}

// ---------------- Kernel 2: one-block-per-batch scan (no inter-block comm) -
// 32 blocks x 1024 threads. Block b owns batch b. Thread (kh = tid>>9,
// c = tid&511) holds W_rec[kh*256 .. +256)[c] in 256 VGPRs
// (1024 thr x 256 = the full 512x512 W_rec per block).
// __launch_bounds__(1024, 4): 4 waves/EU -> 512-VGPR cap, prevents the
// round-5 spill-to-scratch (VGPR_Count=92 tell).
// Per step: h_{t-1} broadcast from LDS (uniform-addr ds_read_b128,
// conflict-free), 256 FMA in 4 chains, LDS partial reduce across k-halves,
// tanh, write out + next-parity LDS. Two barriers/step. Zero global sync.
__global__ __launch_bounds__(1024, 4) void rnn_scan(
    float* __restrict__ out, const float* __restrict__ Wrec) {
  __shared__ float hs[2][D];   // double-buffered h state
  __shared__ float part[D];    // k-half partial sums
  const int b = blockIdx.x;
  const int tid = threadIdx.x;
  const int kh = tid >> 9;     // k-half: waves 0..7 -> 0, waves 8..15 -> 1
  const int c = tid & 511;     // owned output column
  const int k0 = kh * 256;

  // One-time W slice load into registers: wreg[i] = Wrec[(k0+i)*D + c]
  // (coalesced: consecutive tid -> consecutive c).
  float wreg[256];
  {
    const float* wp = Wrec + (size_t)k0 * D + c;
#pragma unroll
    for (int i = 0; i < 256; ++i) wreg[i] = wp[(size_t)i * D];
  }

  float* ob = out + (size_t)b * T * D;

  // ---- t = 0: h0 = tanh(xw_0)
  if (kh == 0) {
    float h = tanhf(ob[c]);
    ob[c] = h;
    hs[0][c] = h;
  }
  __syncthreads();

  for (int t = 1; t < T; ++t) {
    const int cur = (t - 1) & 1, nxt = t & 1;
    // prefetch xw_t (hidden under the FMA loop by the scheduler)
    float xw = 0.f;
    if (kh == 0) xw = ob[(size_t)t * D + c];
    // 256 MACs: W from registers, h broadcast from LDS (uniform address)
    const float4* hp = (const float4*)&hs[cur][k0];
    float a0 = 0.f, a1 = 0.f, a2 = 0.f, a3 = 0.f;
#pragma unroll
    for (int i = 0; i < 64; ++i) {
      const float4 h4 = hp[i];
      a0 += wreg[4 * i + 0] * h4.x;
      a1 += wreg[4 * i + 1] * h4.y;
      a2 += wreg[4 * i + 2] * h4.z;
      a3 += wreg[4 * i + 3] * h4.w;
    }
    const float acc = (a0 + a1) + (a2 + a3);
    // reduce across the two k-halves through LDS
    if (kh == 1) part[c] = acc;
    __syncthreads();
    if (kh == 0) {
      const float h = tanhf(acc + part[c] + xw);
      ob[(size_t)t * D + c] = h;
      hs[nxt][c] = h;
    }
    __syncthreads();
  }
}

extern "C" void kernel_launch(void* const* d_in, const int* in_sizes, int n_in,
                              void* d_out, int out_size, void* d_ws, size_t ws_size,
                              hipStream_t stream) {
  const float* x = (const float*)d_in[0];
  const float* W = (const float*)d_in[1];
  const float* Wrec = (const float*)d_in[2];
  const float* bias = (const float*)d_in[3];
  float* out = (float*)d_out;

  // xw + bias straight into d_out (row = b*T+t matches [B][T][D]).
  xw_gemm<<<dim3(D / 64, (B * T) / 64), 256, 0, stream>>>(x, W, bias, out);

  // Scan: one block per batch, fully self-contained (no cooperative launch,
  // no workspace, no inter-block sync).
  rnn_scan<<<dim3(B), dim3(1024), 0, stream>>>(out, Wrec);
}

// Round 7
// 8368.511 us; speedup vs baseline: 2.9514x; 2.9514x over previous
//
#include <hip/hip_runtime.h>

// Problem constants (from reference): B=32, T=2048, D_IN=D_OUT=512, fp32.
constexpr int B = 32, T = 2048, D = 512;

// ---------------- Kernel 1: xw = x @ W + b, written in-place into d_out ----
__global__ __launch_bounds__(256) void xw_gemm(
    const float* __restrict__ A, const float* __restrict__ W,
    const float* __restrict__ bias, float* __restrict__ C) {
  __shared__ float As[16][68];
  __shared__ float Bs[16][68];
  const int tid = threadIdx.x;
  const int M0 = blockIdx.y * 64, N0 = blockIdx.x * 64;
  const int tn = tid & 15, tm = tid >> 4;
  const int rA = tid >> 2, kA = (tid & 3) << 2;
  const int kB = tid >> 4, nB = (tid & 15) << 2;
  float acc[4][4] = {};
  for (int k0 = 0; k0 < 512; k0 += 16) {
    float4 a4 = *(const float4*)&A[(size_t)(M0 + rA) * 512 + k0 + kA];
    As[kA + 0][rA] = a4.x;
    As[kA + 1][rA] = a4.y;
    As[kA + 2][rA] = a4.z;
    As[kA + 3][rA] = a4.w;
    *(float4*)&Bs[kB][nB] = *(const float4*)&W[(size_t)(k0 + kB) * 512 + N0 + nB];
    __syncthreads();
#pragma unroll
    for (int k = 0; k < 16; ++k) {
      float a0 = As[k][tm * 4 + 0], a1 = As[k][tm * 4 + 1];
      float a2 = As[k][tm * 4 + 2], a3 = As[k][tm * 4 + 3];
      float b0 = Bs[k][tn * 4 + 0], b1 = Bs[k][tn * 4 + 1];
      float b2 = Bs[k][tn * 4 + 2], b3 = Bs[k][tn * 4 + 3];
      acc[0][0] += a0 * b0; acc[0][1] += a0 * b1; acc[0][2] += a0 * b2; acc[0][3] += a0 * b3;
      acc[1][0] += a1 * b0; acc[1][1] += a1 * b1; acc[1][2] += a1 * b2; acc[1][3] += a1 * b3;
      acc[2][0] += a2 * b0; acc[2][1] += a2 * b1; acc[2][2] += a2 * b2; acc[2][3] += a2 * b3;
      acc[3][0] += a3 * b0; acc[3][1] += a3 * b1; acc[3][2] += a3 * b2; acc[3][3] += a3 * b3;
    }
    __syncthreads();
  }
#pragma unroll
  for (int i = 0; i < 4; ++i) {
    const size_t row = (size_t)(M0 + tm * 4 + i);
    float4 v;
    v.x = acc[i][0] + bias[N0 + tn * 4 + 0];
    v.y = acc[i][1] + bias[N0 + tn * 4 + 1];
    v.z = acc[i][2] + bias[N0 + tn * 4 + 2];
    v.w = acc[i][3] + bias[N0 + tn * 4 + 3];
    *(float4*)&C[row * 512 + N0 + tn * 4] = v;
  }
}

// ---------------- Kernel 2: 4-deep batch-pipelined clique scan -------------
// 64 blocks x 512 threads. Clique = blocks with equal (blk & 7) — under
// round-robin dispatch all 8 land on one XCD (exchange becomes L2-local);
// correctness is placement-independent (agent-scope atomics).
// Clique (x): batches [4x, 4x+4); block role = blk>>3 -> cols [64*role,+64).
// Thread (c = tid>>3, kq = tid&7): wreg[64] = W_rec[kq*64..+64)[C0+c].
// Round r = 4 phases; phase s advances batch s one step. Poll loads are
// early-issued one phase ahead; a consumer needs batch-s data a full round
// after publish -> latency hidden. Band-encoded h (value==flag, proven
// round-4 transport): no fences, no flags, no drains.
constexpr int NBLK = 64, NTHR = 512;

__device__ __forceinline__ float ld_f(const float* p) {
  return __hip_atomic_load(p, __ATOMIC_RELAXED, __HIP_MEMORY_SCOPE_AGENT);
}
__device__ __forceinline__ void st_f(float* p, float v) {
  __hip_atomic_store(p, v, __ATOMIC_RELAXED, __HIP_MEMORY_SCOPE_AGENT);
}

__global__ __launch_bounds__(NTHR, 2) void rnn_scan(float* __restrict__ out,
                                                    const float* __restrict__ Wrec,
                                                    float* __restrict__ xbuf) {
  __shared__ float h_s[4][D];  // per-phase staged h, k XOR-swizzled
  const int blk = blockIdx.x;
  const int x = blk & 7;     // clique (== XCD under round-robin)
  const int role = blk >> 3; // 0..7 -> column slice
  const int C0 = role * 64;
  const int B0 = x * 4;
  const int tid = threadIdx.x;
  const int c = tid >> 3;  // local col 0..63
  const int kq = tid & 7;  // k-octant
  const int k0 = kq * 64;

  // W slice into registers (one-time): wreg[i] = Wrec[(k0+i)*D + C0+c]
  float wreg[64];
  {
    const float* wp = Wrec + (size_t)k0 * D + C0 + c;
#pragma unroll
    for (int i = 0; i < 64; ++i) wreg[i] = wp[(size_t)i * D];
  }

  // clique exchange: xb[batch s][parity][512]
  float* xb = xbuf + (size_t)x * 4 * 2 * 512;
  const float OF[4] = {3.f, 9.f, -3.f, -9.f};
  const int ks = tid ^ ((tid >> 6) << 2);  // swizzled LDS index for element tid
  const bool fin = (kq == 0);

  // ---- t = 0: h0 = tanh(xw_0) for the clique's 4 batches; publish parity 0
  if (fin) {
#pragma unroll
    for (int s = 0; s < 4; ++s) {
      const size_t o = ((size_t)(B0 + s) * T) * D + C0 + c;
      float h = tanhf(out[o]);
      out[o] = h;
      st_f(&xb[(s * 2 + 0) * 512 + C0 + c], h + OF[0]);
    }
  }
  // early-issue poll load for round 1 phase 0 (batch 0, parity 0)
  float e = ld_f(&xb[tid]);

  for (int r = 1; r < T; ++r) {
    const int pv = (r - 1) & 1, pc = r & 1;
    const float offR = OF[(r - 1) & 3], offW = OF[r & 3];
#pragma unroll
    for (int s = 0; s < 4; ++s) {
      // prefetch xw_t for this batch (hides under poll/stage/compute)
      float xw = 0.f;
      if (fin) xw = out[((size_t)(B0 + s) * T + r) * D + C0 + c];
      // poll own float until in-band (early-issued value checked first)
      const float* pp = &xb[(s * 2 + pv) * 512 + tid];
      while (!(fabsf(e - offR) < 1.5f)) e = ld_f(pp);
      h_s[s][ks] = e - offR;
      // early-issue the next phase's poll load
      const float* pn = (s < 3) ? &xb[((s + 1) * 2 + pv) * 512 + tid]
                                : &xb[(0 * 2 + pc) * 512 + tid];
      e = ld_f(pn);
      __syncthreads();
      // compute: 64 MACs, W in registers, h broadcast from LDS (swizzled)
      const float* hp = &h_s[s][k0];
      float a0 = 0.f, a1 = 0.f, a2 = 0.f, a3 = 0.f;
#pragma unroll
      for (int i = 0; i < 16; ++i) {
        const float4 h4 = *(const float4*)&hp[(4 * i) ^ (kq << 2)];
        a0 += wreg[4 * i + 0] * h4.x;
        a1 += wreg[4 * i + 1] * h4.y;
        a2 += wreg[4 * i + 2] * h4.z;
        a3 += wreg[4 * i + 3] * h4.w;
      }
      float acc = (a0 + a1) + (a2 + a3);
      acc += __shfl_xor(acc, 1);
      acc += __shfl_xor(acc, 2);
      acc += __shfl_xor(acc, 4);
      if (fin) {
        const float h = tanhf(acc + xw);
        out[((size_t)(B0 + s) * T + r) * D + C0 + c] = h;
        st_f(&xb[(s * 2 + pc) * 512 + C0 + c], h + offW);
      }
    }
  }
}

extern "C" void kernel_launch(void* const* d_in, const int* in_sizes, int n_in,
                              void* d_out, int out_size, void* d_ws, size_t ws_size,
                              hipStream_t stream) {
  const float* x = (const float*)d_in[0];
  const float* W = (const float*)d_in[1];
  const float* Wrec = (const float*)d_in[2];
  const float* bias = (const float*)d_in[3];
  float* out = (float*)d_out;

  // xw + bias straight into d_out (row = b*T+t matches [B][T][D]).
  xw_gemm<<<dim3(D / 64, (B * T) / 64), 256, 0, stream>>>(x, W, bias, out);

  // xbuf: 8 cliques x 4 batches x 2 parities x 512 floats = 128 KB.
  // Zeroed every launch (zero is in no band) -> deterministic replays.
  hipMemsetAsync(d_ws, 0, (size_t)8 * 4 * 2 * 512 * sizeof(float), stream);
  float* xbuf = (float*)d_ws;

  void* args[] = {(void*)&out, (void*)&Wrec, (void*)&xbuf};
  hipLaunchCooperativeKernel(reinterpret_cast<void*>(rnn_scan), dim3(NBLK),
                             dim3(NTHR), args, 0, stream);
}